// Round 6
// baseline (2104.627 us; speedup 1.0000x reference)
//
#include <hip/hip_runtime.h>
#include <hip/hip_bf16.h>

// GCN fused 4-layer kernel for MI355X (gfx950).
// Strategy: pre-aggregate node mixing (A ⊛ h) then bf16 MFMA GEMM per layer,
// all 4 layers fused per 8-batch-element block with h resident in LDS.
// Weights pre-swizzled into MFMA B-fragment order in d_ws (loaded L2->VGPR).
// (6th submission of round-0 kernel: rounds 1-5 were infra failures, no data.)

typedef float fx4 __attribute__((ext_vector_type(4)));
typedef short bx8 __attribute__((ext_vector_type(8)));

#define NROWS   96          // 8 batch elems * 12 nodes
#define XROWB   512         // X buffer row bytes (256 bf16)
#define HROWB   1024        // H buffer row bytes (512 bf16)
#define LDS_X   0
#define LDS_H   49152
#define LDS_TOT 147456

#define WS_AMT  0                       // 4*144 floats (AmatT per layer)
#define WS_W1   4096                    // bf16 frag-ordered weights
#define WS_W2   (WS_W1 + 256*512*2)
#define WS_W3   (WS_W2 + 512*256*2)
#define WS_W4   (WS_W3 + 256*128*2)
#define WS_END  (WS_W4 + 128*48*2)      // = 606208 bytes

__device__ __forceinline__ unsigned short f2bf(float f){
  unsigned int u = __builtin_bit_cast(unsigned int, f);
  u += 0x7fffu + ((u >> 16) & 1u);      // round-to-nearest-even
  return (unsigned short)(u >> 16);
}
__device__ __forceinline__ float bf2f(unsigned short h){
  return __builtin_bit_cast(float, (unsigned int)h << 16);
}
// XOR swizzle: spreads same-column rows across 16B slots (bank-conflict fix).
#define SWZ(byte, row) ((byte) ^ (((row) & 7) << 4))

// ---------------- pre-kernel: Amat + weight swizzle ----------------

template<int K, int Fp, int Fr>
__device__ __forceinline__ void swizz_w(const float* __restrict__ W,
                                        unsigned short* __restrict__ dst){
  constexpr int KG  = K / 32;
  constexpr int TOT = (Fp/16) * KG * 512;
  int stride = (int)(gridDim.x * blockDim.x);
  for (int i = (int)(blockIdx.x*blockDim.x + threadIdx.x); i < TOT; i += stride){
    int j    = i & 7;
    int lane = (i >> 3) & 63;
    int fg   = i >> 9;                  // frag id = nt*KG + g
    int g    = fg % KG;
    int nt   = fg / KG;
    int k    = g*32 + ((lane >> 4) << 3) + j;   // k-bijection (shared w/ A-read)
    int n    = (nt << 4) + (lane & 15);
    float v  = (n < Fr) ? W[k*Fr + n] : 0.0f;
    dst[i] = f2bf(v);
  }
}

__global__ void gcn_prep(
    const float* __restrict__ adj, const float* __restrict__ nv1,
    const float* __restrict__ nv2,
    const float* __restrict__ W1, const float* __restrict__ att1,
    const float* __restrict__ W2, const float* __restrict__ att2,
    const float* __restrict__ W3, const float* __restrict__ att3,
    const float* __restrict__ W4, const float* __restrict__ att4,
    char* __restrict__ ws)
{
  if (blockIdx.x == 0 && threadIdx.x < 12){
    int n = (int)threadIdx.x;
    float s[12]; float mx = -1e30f;
    for (int m = 0; m < 12; ++m){
      float acc = 0.0f;
      for (int k = 0; k < 10; ++k) acc += nv1[n*10+k] * nv2[k*12+m];
      acc = fmaxf(acc, 0.0f);
      s[m] = acc; mx = fmaxf(mx, acc);
    }
    float den = 0.0f;
    for (int m = 0; m < 12; ++m){ s[m] = __expf(s[m]-mx); den += s[m]; }
    float inv = 1.0f/den;
    float* AmT = (float*)(ws + WS_AMT);
    for (int m = 0; m < 12; ++m){
      float a = adj[n*12+m] + s[m]*inv;          // a = adj + softmax(relu(..))
      AmT[0*144 + m*12 + n] = att1[n*12+m] * a;  // store transposed: AmT[m][n]
      AmT[1*144 + m*12 + n] = att2[n*12+m] * a;
      AmT[2*144 + m*12 + n] = att3[n*12+m] * a;
      AmT[3*144 + m*12 + n] = att4[n*12+m] * a;
    }
  }
  swizz_w<256,512,512>(W1, (unsigned short*)(ws + WS_W1));
  swizz_w<512,256,256>(W2, (unsigned short*)(ws + WS_W2));
  swizz_w<256,128,128>(W3, (unsigned short*)(ws + WS_W3));
  swizz_w<128, 48, 40>(W4, (unsigned short*)(ws + WS_W4));
}

// ---------------- main kernel helpers ----------------

// In-place node mixing of one 128-column window (64 col-pairs x 8 batches
// = 512 items, one per thread). Column+batch exclusive ownership -> no
// internal barrier needed. h_agg[b,n,c] = sum_m Amat[n][m] * h[b,m,c].
__device__ __forceinline__ void mix_window(char* buf, const float* __restrict__ Am,
                                           int ROWB, int p0){
  int tid = (int)threadIdx.x;
  int b = tid >> 6;
  int p = p0 + (tid & 63);
  unsigned int hv[12];
  #pragma unroll
  for (int m = 0; m < 12; ++m){
    int row = b*12 + m;
    hv[m] = *(const unsigned int*)(buf + SWZ(row*ROWB + p*4, row));
  }
  float ax[12], ay[12];
  #pragma unroll
  for (int n = 0; n < 12; ++n){ ax[n] = 0.0f; ay[n] = 0.0f; }
  #pragma unroll
  for (int m = 0; m < 12; ++m){
    float hx = bf2f((unsigned short)(hv[m] & 0xffffu));
    float hy = bf2f((unsigned short)(hv[m] >> 16));
    #pragma unroll
    for (int nn = 0; nn < 12; ++nn){
      float c = Am[m*12 + nn];        // uniform -> s_load
      ax[nn] = fmaf(c, hx, ax[nn]);
      ay[nn] = fmaf(c, hy, ay[nn]);
    }
  }
  #pragma unroll
  for (int nn = 0; nn < 12; ++nn){
    int row = b*12 + nn;
    *(unsigned int*)(buf + SWZ(row*ROWB + p*4, row)) =
        (unsigned int)f2bf(ax[nn]) | ((unsigned int)f2bf(ay[nn]) << 16);
  }
}

// One layer: in-place mix of A-buffer (windowed, interleaved into K-loop),
// GEMM via mfma_f32_16x16x32_bf16 (B-frags direct from pre-swizzled global),
// epilogue bias+relu -> bf16 LDS (or fp32 global for the last layer).
template<int K, int F, int NTW, int AROWB, int OROWB, bool TOGLOB>
__device__ __forceinline__ void gemm_layer(char* Ab, const char* wsW,
    const float* __restrict__ Am, const float* __restrict__ bias,
    char* Ob, float* __restrict__ gout, long long rowbase)
{
  constexpr int KG   = K / 32;     // k-steps
  constexpr int NWIN = K / 128;    // 128-col mix windows
  const bx8* __restrict__ Wf = (const bx8*)wsW;
  int tid  = (int)threadIdx.x;
  int lane = tid & 63, wid = tid >> 6;
  int arow = lane & 15, ahi = lane >> 4;
  int col0 = wid * (NTW*16);
  bool active = (col0 < F);        // only last layer has idle waves

  mix_window(Ab, Am, AROWB, 0);    // prologue: window 0
  __syncthreads();

  fx4 acc[6][NTW];
  #pragma unroll
  for (int mt = 0; mt < 6; ++mt)
    #pragma unroll
    for (int t = 0; t < NTW; ++t)
      #pragma unroll
      for (int r = 0; r < 4; ++r) acc[mt][t][r] = 0.0f;

  #pragma unroll
  for (int w = 0; w < NWIN; ++w){
    if (active){
      #pragma unroll
      for (int gs = 0; gs < 4; ++gs){
        int g = 4*w + gs;
        bx8 bfr[NTW];
        #pragma unroll
        for (int t = 0; t < NTW; ++t)
          bfr[t] = Wf[(((col0 >> 4) + t)*KG + g)*64 + lane];
        bx8 afr[6];
        #pragma unroll
        for (int mt = 0; mt < 6; ++mt){
          int row = mt*16 + arow;
          afr[mt] = *(const bx8*)(Ab + SWZ(row*AROWB + g*64 + ahi*16, row));
        }
        #pragma unroll
        for (int mt = 0; mt < 6; ++mt)
          #pragma unroll
          for (int t = 0; t < NTW; ++t)
            acc[mt][t] = __builtin_amdgcn_mfma_f32_16x16x32_bf16(
                             afr[mt], bfr[t], acc[mt][t], 0, 0, 0);
      }
    }
    if (w + 1 < NWIN){               // mix next window (disjoint columns)
      mix_window(Ab, Am, AROWB, (w+1)*64);
      __syncthreads();
    }
  }

  if (active){
    #pragma unroll
    for (int t = 0; t < NTW; ++t){
      int colb = col0 + t*16 + arow;
      float bv;
      if constexpr (TOGLOB) bv = (colb < 40) ? bias[colb] : 0.0f;
      else                  bv = bias[colb];
      #pragma unroll
      for (int mt = 0; mt < 6; ++mt){
        #pragma unroll
        for (int r = 0; r < 4; ++r){
          int row = mt*16 + ahi*4 + r;          // C layout: col=lane&15,
          float v = fmaxf(acc[mt][t][r] + bv, 0.0f); // row=(lane>>4)*4+r (m89)
          if constexpr (TOGLOB){
            if (colb < 40) gout[(rowbase + row)*40 + colb] = v;
          } else {
            *(unsigned short*)(Ob + SWZ(row*OROWB + colb*2, row)) = f2bf(v);
          }
        }
      }
    }
  }
}

__global__ void __launch_bounds__(512, 2) gcn_main(
    const float* __restrict__ x, const char* __restrict__ ws,
    const float* __restrict__ b1, const float* __restrict__ b2,
    const float* __restrict__ b3, const float* __restrict__ b4,
    float* __restrict__ out)
{
  extern __shared__ __align__(16) char lds[];
  char* Xb = lds + LDS_X;        // 48KB: x/xagg -> h2 -> h2agg
  char* Hb = lds + LDS_H;        // 96KB: h1/h1agg -> h3/h3agg
  const float* AmT = (const float*)ws;
  int tid = (int)threadIdx.x;
  long long rowbase = (long long)blockIdx.x * NROWS;
  const float* xsrc = x + rowbase * 256;

  // stage x (fp32 global -> bf16 swizzled LDS), fully coalesced dwordx4
  #pragma unroll
  for (int i = 0; i < 12; ++i){
    int f4 = tid + i*512;
    fx4 v = ((const fx4*)xsrc)[f4];
    int e    = f4 << 2;
    int row  = e >> 8;
    int colb = (e & 255) * 2;
    unsigned long long pk =
        (unsigned long long)((unsigned int)f2bf(v.x) | ((unsigned int)f2bf(v.y) << 16)) |
        ((unsigned long long)((unsigned int)f2bf(v.z) | ((unsigned int)f2bf(v.w) << 16)) << 32);
    *(unsigned long long*)(Xb + SWZ(row*XROWB + colb, row)) = pk;
  }
  __syncthreads();

  // L1: [96,256]x[256,512] -> Hb
  gemm_layer<256,512,4,XROWB,HROWB,false>(Xb, ws+WS_W1, AmT+0,   b1, Hb, nullptr, 0);
  __syncthreads();
  // L2: [96,512]x[512,256] -> Xb
  gemm_layer<512,256,2,HROWB,XROWB,false>(Hb, ws+WS_W2, AmT+144, b2, Xb, nullptr, 0);
  __syncthreads();
  // L3: [96,256]x[256,128] -> Hb (packed rows of 256B)
  gemm_layer<256,128,1,XROWB,256,false>(Xb, ws+WS_W3, AmT+288, b3, Hb, nullptr, 0);
  __syncthreads();
  // L4: [96,128]x[128,48->40] -> global out (fp32, relu)
  gemm_layer<128, 48,1,256,0,true>(Hb, ws+WS_W4, AmT+432, b4, nullptr, out, rowbase);
}

// ---------------- host ----------------

extern "C" void kernel_launch(void* const* d_in, const int* in_sizes, int n_in,
                              void* d_out, int out_size, void* d_ws, size_t ws_size,
                              hipStream_t stream)
{
  const float* x    = (const float*)d_in[0];
  const float* adj  = (const float*)d_in[1];
  const float* nv1  = (const float*)d_in[2];
  const float* nv2  = (const float*)d_in[3];
  const float* W1   = (const float*)d_in[4];
  const float* att1 = (const float*)d_in[5];
  const float* b1   = (const float*)d_in[6];
  const float* W2   = (const float*)d_in[7];
  const float* att2 = (const float*)d_in[8];
  const float* b2   = (const float*)d_in[9];
  const float* W3   = (const float*)d_in[10];
  const float* att3 = (const float*)d_in[11];
  const float* b3   = (const float*)d_in[12];
  const float* W4   = (const float*)d_in[13];
  const float* att4 = (const float*)d_in[14];
  const float* b4   = (const float*)d_in[15];
  char*  ws  = (char*)d_ws;
  float* out = (float*)d_out;

  if (ws_size < (size_t)WS_END) return;  // need ~592KB scratch

  (void)hipFuncSetAttribute((const void*)gcn_main,
                            hipFuncAttributeMaxDynamicSharedMemorySize, LDS_TOT);

  gcn_prep<<<256, 256, 0, stream>>>(adj, nv1, nv2, W1, att1, W2, att2,
                                    W3, att3, W4, att4, ws);
  gcn_main<<<65536/8, 512, LDS_TOT, stream>>>(x, ws, b1, b2, b3, b4, out);
}